// Round 2
// 151.941 us; speedup vs baseline: 1.3828x; 1.3828x over previous
//
#include <hip/hip_runtime.h>

#define NFFT    4096
#define NBINS   2049
#define TFRAMES 4096
#define HOP     1024
#define LFULL   4197376   // (TFRAMES-1)*HOP + NFFT
#define LOUT    4193280   // LFULL - NFFT  (== out_size/2 exactly)
#define CROP    2048      // NFFT/2
#define RS      2064      // transposed row stride in floats (16B-aligned rows)
#define P0TAIL  4192256   // last even-group tile ends here (4096*1022-2048+8192)

// ---- legacy per-phase LDS swizzles (fallback fft_reg path) ----
__device__ __forceinline__ int SW1(int p) {
    return p ^ (((p >> 6) & 3) | (((p >> 9) & 3) << 2) | (((p >> 8) & 1) << 4));
}
__device__ __forceinline__ int SW2(int p) {
    return p ^ (((p >> 8) & 3) << 3);
}

// radix-4 DIT butterfly, no twiddle (fallback path)
__device__ __forceinline__ void b4(float& x0r, float& x0i, float& x1r, float& x1i,
                                   float& x2r, float& x2i, float& x3r, float& x3i) {
    float a0r = x0r + x2r, a0i = x0i + x2i;
    float a1r = x0r - x2r, a1i = x0i - x2i;
    float a2r = x1r + x3r, a2i = x1i + x3i;
    float a3r = x1r - x3r, a3i = x1i - x3i;
    x0r = a0r + a2r;  x0i = a0i + a2i;
    x1r = a1r - a3i;  x1i = a1i + a3r;
    x2r = a0r - a2r;  x2i = a0i - a2i;
    x3r = a1r + a3i;  x3i = a1i - a3r;
}

__device__ __forceinline__ void b4t(float& x0r, float& x0i, float& x1r, float& x1i,
                                    float& x2r, float& x2i, float& x3r, float& x3i,
                                    float c1, float s1) {
    float c2 = c1 * c1 - s1 * s1, s2 = 2.0f * c1 * s1;
    float c3 = c2 * c1 - s2 * s1, s3 = c2 * s1 + s2 * c1;
    float t1r = x1r * c1 - x1i * s1, t1i = x1r * s1 + x1i * c1;
    float t2r = x2r * c2 - x2i * s2, t2i = x2r * s2 + x2i * c2;
    float t3r = x3r * c3 - x3i * s3, t3i = x3r * s3 + x3i * c3;
    float a0r = x0r + t2r, a0i = x0i + t2i;
    float a1r = x0r - t2r, a1i = x0i - t2i;
    float a2r = t1r + t3r, a2i = t1i + t3i;
    float a3r = t1r - t3r, a3i = t1i - t3i;
    x0r = a0r + a2r;  x0i = a0i + a2i;
    x1r = a1r - a3i;  x1i = a1i + a3r;
    x2r = a0r - a2r;  x2i = a0i - a2i;
    x3r = a1r + a3i;  x3i = a1i - a3r;
}

#define C16_INIT { 1.0f,  0.923879532511287f,  0.707106781186548f,  0.382683432365090f, \
                   0.0f, -0.382683432365090f, -0.707106781186548f, -0.923879532511287f, \
                  -1.0f, -0.923879532511287f, -0.707106781186548f, -0.382683432365090f, \
                   0.0f,  0.382683432365090f,  0.707106781186548f,  0.923879532511287f }
#define S16_INIT { 0.0f,  0.382683432365090f,  0.707106781186548f,  0.923879532511287f, \
                   1.0f,  0.923879532511287f,  0.707106781186548f,  0.382683432365090f, \
                   0.0f, -0.382683432365090f, -0.707106781186548f, -0.923879532511287f, \
                  -1.0f, -0.923879532511287f, -0.707106781186548f, -0.382683432365090f }

// 8-point inverse DFT (kernel e^{+2pi i km/8}), natural in/out order
__device__ __forceinline__ void dft8(float* xr, float* xi) {
    const float r = 0.70710678118654752f;
    float t0r = xr[0]+xr[4], t0i = xi[0]+xi[4];
    float t1r = xr[0]-xr[4], t1i = xi[0]-xi[4];
    float t2r = xr[2]+xr[6], t2i = xi[2]+xi[6];
    float t3r = xr[2]-xr[6], t3i = xi[2]-xi[6];
    float E0r = t0r+t2r, E0i = t0i+t2i;
    float E2r = t0r-t2r, E2i = t0i-t2i;
    float E1r = t1r-t3i, E1i = t1i+t3r;
    float E3r = t1r+t3i, E3i = t1i-t3r;
    float u0r = xr[1]+xr[5], u0i = xi[1]+xi[5];
    float u1r = xr[1]-xr[5], u1i = xi[1]-xi[5];
    float u2r = xr[3]+xr[7], u2i = xi[3]+xi[7];
    float u3r = xr[3]-xr[7], u3i = xi[3]-xi[7];
    float O0r = u0r+u2r, O0i = u0i+u2i;
    float O2r = u0r-u2r, O2i = u0i-u2i;
    float O1r = u1r-u3i, O1i = u1i+u3r;
    float O3r = u1r+u3i, O3i = u1i-u3r;
    float w1r =  r*(O1r - O1i), w1i = r*(O1r + O1i);   // * e^{i pi/4}
    float w2r = -O2i,           w2i = O2r;             // * i
    float w3r = -r*(O3r + O3i), w3i = r*(O3r - O3i);   // * e^{i 3pi/4}
    xr[0] = E0r + O0r;  xi[0] = E0i + O0i;
    xr[4] = E0r - O0r;  xi[4] = E0i - O0i;
    xr[1] = E1r + w1r;  xi[1] = E1i + w1i;
    xr[5] = E1r - w1r;  xi[5] = E1i - w1i;
    xr[2] = E2r + w2r;  xi[2] = E2i + w2i;
    xr[6] = E2r - w2r;  xi[6] = E2i - w2i;
    xr[3] = E3r + w3r;  xi[3] = E3i + w3i;
    xr[7] = E3r - w3r;  xi[7] = E3i - w3i;
}

// ---------------- transpose: z[ch][f][t] -> zt[ch][t][f], 64x64 float4 tiles ----------------
__global__ __launch_bounds__(256) void transpose64(
    const float* __restrict__ z, float* __restrict__ zt)
{
    __shared__ float tile[64][65];
    const int ch = blockIdx.z;
    const int f0 = blockIdx.x * 64;
    const int t0 = blockIdx.y * 64;
    const int tx = threadIdx.x & 15;
    const int ty = threadIdx.x >> 4;
    const float* src = z + (size_t)ch * NBINS * TFRAMES;
    float* dst = zt + (size_t)ch * TFRAMES * RS;

    #pragma unroll
    for (int k = 0; k < 4; ++k) {
        int fl = ty + 16 * k;
        float4 v = *(const float4*)(src + (size_t)(f0 + fl) * TFRAMES + t0 + 4 * tx);
        tile[fl][4 * tx + 0] = v.x;
        tile[fl][4 * tx + 1] = v.y;
        tile[fl][4 * tx + 2] = v.z;
        tile[fl][4 * tx + 3] = v.w;
    }
    __syncthreads();
    #pragma unroll
    for (int k = 0; k < 4; ++k) {
        int tl = ty + 16 * k;
        float4 v = make_float4(tile[4 * tx + 0][tl], tile[4 * tx + 1][tl],
                               tile[4 * tx + 2][tl], tile[4 * tx + 3][tl]);
        *(float4*)(dst + (size_t)(t0 + tl) * RS + f0 + 4 * tx) = v;
    }
}

__global__ __launch_bounds__(256) void edge2048(
    const float* __restrict__ z, float* __restrict__ zt)
{
    int i = blockIdx.x * 256 + threadIdx.x;      // 0 .. 8191
    int ch = i >> 12, t = i & 4095;
    zt[(size_t)ch * TFRAMES * RS + (size_t)t * RS + 2048] =
        z[(size_t)ch * NBINS * TFRAMES + (size_t)2048 * TFRAMES + t];
}

// ---------------- real-IFFT path: 4 frames/block via 2048-pt complex IFFT ----------------
// Hermitian structure: Im(ifft) = (b0 + (-1)^n b2048)/N  -> computed in normalize.
// Re(ifft) = irfft(Hermitianized half): pack Y[k] = A[k] + i B[k], k<2048,
//   A[k]=H[k]+conj(H[2048-k]), B[k]=(H[k]-conj(H[2048-k]))e^{2pi i k/4096},
// then y = sum_k Y[k] e^{2pi i km/2048}; x[2m]=Re(y)/4096, x[2m+1]=Im(y)/4096.
// 2048 = 8*8*8*4, 8 pts/thread, 3 LDS shuffles (<=2-way banked), dbuf LDS, 3 barriers/frame.
// OLA tiling: frame t=4g+k4, m=T+256mp -> sample n=512mp+2T(+1); slot=mp+2k4 (0..13),
// 512-sample slots; group tile [Sc, Sc+8192), Sc=4096g-2048; parity planes as before.
__global__ __launch_bounds__(256, 3) void fft4(
    const float* __restrict__ zt,      // [2][TFRAMES][RS]
    float* __restrict__ planes)        // [2 planes][LOUT] (real channel only)
{
    __shared__ float LRe[2][2048];
    __shared__ float LIm[2][2048];
    const int g = blockIdx.x;
    const int T = threadIdx.x;
    const float C16[16] = C16_INIT;
    const float S16[16] = S16_INIT;

    // twiddle bases depend only on T -> hoisted out of the frame loop
    float cT, sT;  __sincosf((float)T * (6.283185307179586f / 4096.0f), &sT, &cT);
    float c2, s2;  __sincosf((float)(T >> 5) * (6.283185307179586f / 64.0f), &s2, &c2);
    const int alpha = ((T >> 2) & 7) | ((T >> 5) << 3);
    float c3, s3;  __sincosf((float)alpha * (6.283185307179586f / 512.0f), &s3, &c3);
    float cD, sD;  __sincosf((float)T * (6.283185307179586f / 2048.0f), &sD, &cD);

    const float K   = 4.4703483581542969e-8f;   // 0.5*(1.5/NFFT)/NFFT
    const float cd4 = 0.99999882345170188f;     // cos(2pi/4096)
    const float sd4 = 1.5339801862847655e-3f;   // sin(2pi/4096)

    float accE[14], accO[14];
    #pragma unroll
    for (int i = 0; i < 14; ++i) { accE[i] = 0.0f; accO[i] = 0.0f; }

    int b = 0;
    #pragma unroll
    for (int k4 = 0; k4 < 4; ++k4) {
        const int t = 4 * g + k4;
        const float* rowr = zt + (size_t)t * RS;
        const float* rowi = zt + (size_t)TFRAMES * RS + (size_t)t * RS;
        float xr[8], xi[8];

        // ---- stage 1: load + Y-pack + 8-pt DFT over kA (k = T + 256*kA) ----
        #pragma unroll
        for (int kA = 0; kA < 8; ++kA) {
            int k = T + (kA << 8);
            float u  = rowr[k],        v  = rowi[k];
            float pp = rowr[2048 - k], qq = rowi[2048 - k];
            if (T == 0 && kA == 0) { v = 0.0f; qq = 0.0f; }  // bins 0/2048: drop imag
            float ck = cT * C16[kA] - sT * S16[kA];          // e^{2pi i k/4096}
            float sk = sT * C16[kA] + cT * S16[kA];
            float dr = u - pp, di = v + qq;
            xr[kA] = (u + pp) - (dr * sk + di * ck);
            xi[kA] = (v - qq) + (dr * ck - di * sk);
        }
        dft8(xr, xi);
        #pragma unroll
        for (int m1 = 0; m1 < 8; ++m1) {
            int a = (m1 << 8) | T;
            LRe[b][a] = xr[m1];  LIm[b][a] = xi[m1];
        }
        __syncthreads();

        // ---- stage 2: 8-pt DFT over kB, pre-twiddle e^{2pi i kB m1/64}, m1=T>>5 ----
        {
            float cw = 1.0f, sw = 0.0f;
            #pragma unroll
            for (int kB = 0; kB < 8; ++kB) {
                int a = ((T >> 5) << 8) | (kB << 5) | (T & 31);
                float vr = LRe[b][a], vi = LIm[b][a];
                xr[kB] = vr * cw - vi * sw;
                xi[kB] = vr * sw + vi * cw;
                float ncw = cw * c2 - sw * s2;
                sw = cw * s2 + sw * c2;  cw = ncw;
            }
        }
        dft8(xr, xi);
        b ^= 1;
        #pragma unroll
        for (int m2 = 0; m2 < 8; ++m2) {
            int a = (m2 << 8) | T;
            a ^= ((a >> 5) & 7) << 2;          // swizzle: both sides <=2-way
            LRe[b][a] = xr[m2];  LIm[b][a] = xi[m2];
        }
        __syncthreads();

        // ---- stage 3: 8-pt DFT over kC, pre-twiddle e^{2pi i kC alpha/512} ----
        {
            float cw = 1.0f, sw = 0.0f;
            #pragma unroll
            for (int kC = 0; kC < 8; ++kC) {
                int a = ((T >> 5) << 8) | (((T >> 2) & 7) << 5) | (kC << 2) | (T & 3);
                a ^= ((a >> 5) & 7) << 2;
                float vr = LRe[b][a], vi = LIm[b][a];
                xr[kC] = vr * cw - vi * sw;
                xi[kC] = vr * sw + vi * cw;
                float ncw = cw * c3 - sw * s3;
                sw = cw * s3 + sw * c3;  cw = ncw;
            }
        }
        dft8(xr, xi);
        b ^= 1;
        #pragma unroll
        for (int m3 = 0; m3 < 8; ++m3) {
            int a = (m3 << 8) | T;
            a ^= (a >> 5) & 3;                 // swizzle: both sides <=2-way
            LRe[b][a] = xr[m3];  LIm[b][a] = xi[m3];
        }
        __syncthreads();

        // ---- stage 4: two 4-pt DFTs over kD + window + register OLA ----
        #pragma unroll
        for (int hi = 0; hi < 2; ++hi) {
            // base twiddle wb = e^{2pi i (T + 256*hi)/2048}
            float cb = hi ? (cD * C16[2] - sD * S16[2]) : cD;
            float sb = hi ? (sD * C16[2] + cD * S16[2]) : sD;
            float zr[4], zi[4];
            float cw = 1.0f, sw = 0.0f;
            #pragma unroll
            for (int kD = 0; kD < 4; ++kD) {
                int a = (((T >> 6) + 4 * hi) << 8) | (((T >> 3) & 7) << 5) | ((T & 7) << 2) | kD;
                a ^= (a >> 5) & 3;
                float vr = LRe[b][a], vi = LIm[b][a];
                zr[kD] = vr * cw - vi * sw;
                zi[kD] = vr * sw + vi * cw;
                float ncw = cw * cb - sw * sb;
                sw = cw * sb + sw * cb;  cw = ncw;
            }
            float e0r = zr[0] + zr[2], e0i = zi[0] + zi[2];
            float e1r = zr[0] - zr[2], e1i = zi[0] - zi[2];
            float o0r = zr[1] + zr[3], o0i = zi[1] + zi[3];
            float o1r = zr[1] - zr[3], o1i = zi[1] - zi[3];
            float yr[4], yi[4];
            yr[0] = e0r + o0r;  yi[0] = e0i + o0i;
            yr[2] = e0r - o0r;  yi[2] = e0i - o0i;
            yr[1] = e1r - o1i;  yi[1] = e1i + o1r;
            yr[3] = e1r + o1i;  yi[3] = e1i - o1r;
            #pragma unroll
            for (int m4 = 0; m4 < 4; ++m4) {
                int mp = hi + 2 * m4;          // m = T + 256*mp
                float cm = cD * C16[2 * mp] - sD * S16[2 * mp];   // cos(2pi m/2048)
                float sm = sD * C16[2 * mp] + cD * S16[2 * mp];
                float we = (1.0f - cm) * K;                        // window(2m)*scale
                float co = cm * cd4 - sm * sd4;
                float wo = (1.0f - co) * K;                        // window(2m+1)*scale
                int slot = mp + 2 * k4;
                accE[slot] += yr[m4] * we;
                accO[slot] += yi[m4] * wo;
            }
        }
        b ^= 1;
    }

    // ---- plain coalesced float2 stores; slots 14,15 zero-pad tile the plane ----
    const int plane = g & 1;
    float* pr = planes + (size_t)plane * LOUT;
    const int Sc = (g << 12) - 2048;
    #pragma unroll
    for (int s = 0; s < 16; ++s) {
        int Q = Sc + (s << 9) + 2 * T;
        if ((unsigned)Q < (unsigned)LOUT) {
            float2 v;
            v.x = (s < 14) ? accE[s] : 0.0f;
            v.y = (s < 14) ? accO[s] : 0.0f;
            *(float2*)(pr + Q) = v;
        }
    }
}

// ---------------- sum 2 planes (real) + analytic imag channel + normalize ----------------
__global__ __launch_bounds__(256) void normalize_planes(
    const float* __restrict__ planes,    // [2][LOUT]
    const float* __restrict__ z,         // original input: b rows for imag channel
    const float* __restrict__ window,
    float* __restrict__ out)
{
    int idx = blockIdx.x * 256 + threadIdx.x;
    int p = idx * 4;
    if (p >= LOUT) return;
    const float* b0  = z + (size_t)NBINS * TFRAMES;                            // z[1][0][t]
    const float* b2k = z + (size_t)NBINS * TFRAMES + (size_t)2048 * TFRAMES;   // z[1][2048][t]
    float4 a0 = *(const float4*)(planes + p);
    float4 a1 = *(const float4*)(planes + (size_t)LOUT + p);
    float re[4] = {a0.x + a1.x, a0.y + a1.y, a0.z + a1.z, a0.w + a1.w};
    const float INV_N = 1.0f / 4096.0f;
    if (p >= 1024 && p < LOUT - 1024) {
        const float inv = (float)NFFT / 3.0f;          // interior wsum = 3/4096 exactly
        float im[4];
        #pragma unroll
        for (int e = 0; e < 4; ++e) {
            int P = p + e + CROP;
            int th = P >> 10;                          // t_hi; frames th-3..th overlap
            int n0 = P & 1023;
            float sn, cn;
            __sincosf((float)n0 * (6.283185307179586f / 4096.0f), &sn, &cn);
            const float WK = 1.8310546875e-4f;         // 0.5*1.5/4096
            // w[n0+1024j]: cos terms {cn, -sn, -cn, sn}
            float w0 = (1.0f - cn) * WK;
            float w1 = (1.0f + sn) * WK;
            float w2 = (1.0f + cn) * WK;
            float w3 = (1.0f - sn) * WK;
            float s1 = w0 * b0[th]  + w1 * b0[th - 1]  + w2 * b0[th - 2]  + w3 * b0[th - 3];
            float s2 = w0 * b2k[th] + w1 * b2k[th - 1] + w2 * b2k[th - 2] + w3 * b2k[th - 3];
            float sgn = (P & 1) ? -1.0f : 1.0f;
            im[e] = (s1 + sgn * s2) * (1.0f / 3.0f);   // (1/4096)*(4096/3)
            re[e] *= inv;
        }
        *(float4*)(out + p) = make_float4(re[0], re[1], re[2], re[3]);
        *(float4*)(out + (size_t)LOUT + p) = make_float4(im[0], im[1], im[2], im[3]);
    } else {
        for (int e = 0; e < 4; ++e) {
            int P = p + e + CROP;
            int t_hi = min(TFRAMES - 1, P >> 10);
            int t_lo = max(0, (P - (NFFT - HOP)) >> 10);
            float ws = 0.0f, s1 = 0.0f, s2 = 0.0f;
            for (int tt = t_lo; tt <= t_hi; ++tt) {
                float w = window[P - (tt << 10)];
                ws += w;
                s1 += w * b0[tt];
                s2 += w * b2k[tt];
            }
            float inv = (ws >= 1e-6f) ? (1.0f / ws) : 1.0f;
            float sgn = (P & 1) ? -1.0f : 1.0f;
            out[p + e]                 = re[e] * inv;
            out[(size_t)LOUT + p + e]  = (s1 + sgn * s2) * INV_N * inv;
        }
    }
}

// ================= fallback path (ws too small for planes): atomic version =================
__global__ __launch_bounds__(256) void fft_reg(
    const float* __restrict__ zt, float* __restrict__ out)
{
    __shared__ float LRe[NFFT];
    __shared__ float LIm[NFFT];
    const int t = blockIdx.x;
    const int T = threadIdx.x;
    const float C16[16] = C16_INIT;
    const float S16[16] = S16_INIT;
    const float* rowr = zt + (size_t)t * RS;
    const float* rowi = zt + (size_t)TFRAMES * RS + (size_t)t * RS;
    float xr[16], xi[16];
    #pragma unroll
    for (int m = 0; m < 16; ++m) {
        int r = ((m & 3) << 2) | (m >> 2);
        int n = (m << 8) + T;
        if (n <= 2048) { xr[r] = rowr[n]; xi[r] = rowi[n]; }
        else { int f = NFFT - n; xr[r] = rowr[f]; xi[r] = -rowi[f]; }
    }
    #pragma unroll
    for (int a = 0; a < 4; ++a)
        b4(xr[4*a], xi[4*a], xr[4*a+1], xi[4*a+1], xr[4*a+2], xi[4*a+2], xr[4*a+3], xi[4*a+3]);
    b4(xr[0], xi[0], xr[4], xi[4], xr[8], xi[8], xr[12], xi[12]);
    #pragma unroll
    for (int r0 = 1; r0 < 4; ++r0)
        b4t(xr[r0], xi[r0], xr[r0+4], xi[r0+4], xr[r0+8], xi[r0+8], xr[r0+12], xi[r0+12],
            C16[r0], S16[r0]);
    {
        int G = ((T & 3) << 6) | (((T >> 2) & 3) << 4) | (((T >> 4) & 3) << 2) | ((T >> 6) & 3);
        int p0 = G << 4;
        #pragma unroll
        for (int r = 0; r < 16; ++r) { int a = SW1(p0 + r); LRe[a] = xr[r]; LIm[a] = xi[r]; }
    }
    __syncthreads();
    const int H = T >> 4, j = T & 15;
    #pragma unroll
    for (int s = 0; s < 16; ++s) { int a = SW1((H << 8) + (s << 4) + j); xr[s] = LRe[a]; xi[s] = LIm[a]; }
    float cb, sb;
    __sincosf((float)j * (6.283185307179586f / 256.0f), &sb, &cb);
    float cd = cb * cb - sb * sb, sd = 2.0f * cb * sb;
    float c2s = cd * cd - sd * sd, s2s = 2.0f * cd * sd;
    if (j == 0) {
        #pragma unroll
        for (int a = 0; a < 4; ++a)
            b4(xr[4*a], xi[4*a], xr[4*a+1], xi[4*a+1], xr[4*a+2], xi[4*a+2], xr[4*a+3], xi[4*a+3]);
    } else {
        #pragma unroll
        for (int a = 0; a < 4; ++a)
            b4t(xr[4*a], xi[4*a], xr[4*a+1], xi[4*a+1], xr[4*a+2], xi[4*a+2], xr[4*a+3], xi[4*a+3],
                c2s, s2s);
    }
    #pragma unroll
    for (int s0 = 0; s0 < 4; ++s0) {
        float c = cb * C16[s0] - sb * S16[s0];
        float s = sb * C16[s0] + cb * S16[s0];
        if (s0 == 0 && j == 0) b4(xr[0], xi[0], xr[4], xi[4], xr[8], xi[8], xr[12], xi[12]);
        else b4t(xr[s0], xi[s0], xr[s0+4], xi[s0+4], xr[s0+8], xi[s0+8], xr[s0+12], xi[s0+12], c, s);
    }
    __syncthreads();
    #pragma unroll
    for (int s = 0; s < 16; ++s) { int a = SW2((H << 8) + (s << 4) + j); LRe[a] = xr[s]; LIm[a] = xi[s]; }
    __syncthreads();
    #pragma unroll
    for (int m = 0; m < 16; ++m) { int a = SW2((m << 8) + T); xr[m] = LRe[a]; xi[m] = LIm[a]; }
    float c5, s5;
    __sincosf((float)T * (6.283185307179586f / 4096.0f), &s5, &c5);
    float cq = c5 * c5 - s5 * s5, sq = 2.0f * c5 * s5;
    float c4s = cq * cq - sq * sq, s4s = 2.0f * cq * sq;
    if (T == 0) {
        #pragma unroll
        for (int a = 0; a < 4; ++a)
            b4(xr[4*a], xi[4*a], xr[4*a+1], xi[4*a+1], xr[4*a+2], xi[4*a+2], xr[4*a+3], xi[4*a+3]);
    } else {
        #pragma unroll
        for (int a = 0; a < 4; ++a)
            b4t(xr[4*a], xi[4*a], xr[4*a+1], xi[4*a+1], xr[4*a+2], xi[4*a+2], xr[4*a+3], xi[4*a+3],
                c4s, s4s);
    }
    #pragma unroll
    for (int m0 = 0; m0 < 4; ++m0) {
        float c = c5 * C16[m0] - s5 * S16[m0];
        float s = s5 * C16[m0] + c5 * S16[m0];
        if (m0 == 0 && T == 0) b4(xr[0], xi[0], xr[4], xi[4], xr[8], xi[8], xr[12], xi[12]);
        else b4t(xr[m0], xi[m0], xr[m0+4], xi[m0+4], xr[m0+8], xi[m0+8], xr[m0+12], xi[m0+12], c, s);
    }
    const float K = 4.4703483581542969e-8f;
    const int base = (t << 10) - CROP;
    #pragma unroll
    for (int m = 0; m < 16; ++m) {
        float cn = c5 * C16[m] - s5 * S16[m];
        float wn = (1.0f - cn) * K;
        int P = base + (m << 8) + T;
        if (P >= 0 && P < LOUT) {
            atomicAdd(&out[P],        xr[m] * wn);
            atomicAdd(&out[LOUT + P], xi[m] * wn);
        }
    }
}

__global__ __launch_bounds__(256) void normalize_inplace(
    const float* __restrict__ window, float* __restrict__ out)
{
    int idx = blockIdx.x * 256 + threadIdx.x;
    int p = idx * 4;
    if (p >= LOUT) return;
    if (p >= 1024 && p < LOUT - 1024) {
        const float inv = (float)NFFT / 3.0f;
        float4* o0 = (float4*)(out + p);
        float4* o1 = (float4*)(out + LOUT + p);
        float4 a = *o0, b = *o1;
        a.x *= inv; a.y *= inv; a.z *= inv; a.w *= inv;
        b.x *= inv; b.y *= inv; b.z *= inv; b.w *= inv;
        *o0 = a; *o1 = b;
    } else {
        for (int e = 0; e < 4; ++e) {
            int pe = p + e;
            int P = pe + CROP;
            int t_hi = min(TFRAMES - 1, P >> 10);
            int t_lo = max(0, (P - (NFFT - HOP)) >> 10);
            float ws = 0.0f;
            for (int tt = t_lo; tt <= t_hi; ++tt) ws += window[P - (tt << 10)];
            float inv = (ws >= 1e-6f) ? (1.0f / ws) : 1.0f;
            out[pe]        *= inv;
            out[LOUT + pe] *= inv;
        }
    }
}

extern "C" void kernel_launch(void* const* d_in, const int* in_sizes, int n_in,
                              void* d_out, int out_size, void* d_ws, size_t ws_size,
                              hipStream_t stream) {
    const float* z      = (const float*)d_in[0];
    const float* window = (const float*)d_in[1];
    float* out = (float*)d_out;

    const size_t zt_floats = (size_t)2 * TFRAMES * RS;            // 16,908,288
    const size_t ws_need_B = zt_floats * sizeof(float);           // 67.6 MB (atomic path)
    const size_t ws_need_A = (zt_floats + (size_t)2 * LOUT) * sizeof(float);  // 101.2 MB

    if (ws_size >= ws_need_A) {
        float* zt     = (float*)d_ws;
        float* planes = zt + zt_floats;
        transpose64<<<dim3(32, 64, 2), 256, 0, stream>>>(z, zt);
        edge2048<<<32, 256, 0, stream>>>(z, zt);
        // plane-0 tail gap [P0TAIL, LOUT): no even tile covers it -> zero
        hipMemsetAsync(planes + P0TAIL, 0, (size_t)(LOUT - P0TAIL) * sizeof(float), stream);
        // plane-1 head gap [0, 2048): no odd tile covers it -> zero
        hipMemsetAsync(planes + (size_t)LOUT, 0, (size_t)2048 * sizeof(float), stream);
        fft4<<<TFRAMES / 4, 256, 0, stream>>>(zt, planes);
        normalize_planes<<<(LOUT / 4 + 255) / 256, 256, 0, stream>>>(planes, z, window, out);
    } else if (ws_size >= ws_need_B) {
        float* zt = (float*)d_ws;
        hipMemsetAsync(out, 0, (size_t)2 * LOUT * sizeof(float), stream);
        transpose64<<<dim3(32, 64, 2), 256, 0, stream>>>(z, zt);
        edge2048<<<32, 256, 0, stream>>>(z, zt);
        fft_reg<<<TFRAMES, 256, 0, stream>>>(zt, out);
        normalize_inplace<<<(LOUT / 4 + 255) / 256, 256, 0, stream>>>(window, out);
    }
}

// Round 3
// 147.093 us; speedup vs baseline: 1.4283x; 1.0330x over previous
//
#include <hip/hip_runtime.h>

#define NFFT    4096
#define NBINS   2049
#define TFRAMES 4096
#define HOP     1024
#define LFULL   4197376   // (TFRAMES-1)*HOP + NFFT
#define LOUT    4193280   // LFULL - NFFT  (== out_size/2 exactly)
#define CROP    2048      // NFFT/2
#define RS      2064      // transposed row stride in floats (16B-aligned rows)
#define P0TAIL  4192256   // last even-group tile ends here (4096*1022-2048+8192)

// ---- legacy per-phase LDS swizzles (fallback fft_reg path) ----
__device__ __forceinline__ int SW1(int p) {
    return p ^ (((p >> 6) & 3) | (((p >> 9) & 3) << 2) | (((p >> 8) & 1) << 4));
}
__device__ __forceinline__ int SW2(int p) {
    return p ^ (((p >> 8) & 3) << 3);
}

// radix-4 DIT butterfly, no twiddle (fallback path)
__device__ __forceinline__ void b4(float& x0r, float& x0i, float& x1r, float& x1i,
                                   float& x2r, float& x2i, float& x3r, float& x3i) {
    float a0r = x0r + x2r, a0i = x0i + x2i;
    float a1r = x0r - x2r, a1i = x0i - x2i;
    float a2r = x1r + x3r, a2i = x1i + x3i;
    float a3r = x1r - x3r, a3i = x1i - x3i;
    x0r = a0r + a2r;  x0i = a0i + a2i;
    x1r = a1r - a3i;  x1i = a1i + a3r;
    x2r = a0r - a2r;  x2i = a0i - a2i;
    x3r = a1r + a3i;  x3i = a1i - a3r;
}

__device__ __forceinline__ void b4t(float& x0r, float& x0i, float& x1r, float& x1i,
                                    float& x2r, float& x2i, float& x3r, float& x3i,
                                    float c1, float s1) {
    float c2 = c1 * c1 - s1 * s1, s2 = 2.0f * c1 * s1;
    float c3 = c2 * c1 - s2 * s1, s3 = c2 * s1 + s2 * c1;
    float t1r = x1r * c1 - x1i * s1, t1i = x1r * s1 + x1i * c1;
    float t2r = x2r * c2 - x2i * s2, t2i = x2r * s2 + x2i * c2;
    float t3r = x3r * c3 - x3i * s3, t3i = x3r * s3 + x3i * c3;
    float a0r = x0r + t2r, a0i = x0i + t2i;
    float a1r = x0r - t2r, a1i = x0i - t2i;
    float a2r = t1r + t3r, a2i = t1i + t3i;
    float a3r = t1r - t3r, a3i = t1i - t3i;
    x0r = a0r + a2r;  x0i = a0i + a2i;
    x1r = a1r - a3i;  x1i = a1i + a3r;
    x2r = a0r - a2r;  x2i = a0i - a2i;
    x3r = a1r + a3i;  x3i = a1i - a3r;
}

#define C16_INIT { 1.0f,  0.923879532511287f,  0.707106781186548f,  0.382683432365090f, \
                   0.0f, -0.382683432365090f, -0.707106781186548f, -0.923879532511287f, \
                  -1.0f, -0.923879532511287f, -0.707106781186548f, -0.382683432365090f, \
                   0.0f,  0.382683432365090f,  0.707106781186548f,  0.923879532511287f }
#define S16_INIT { 0.0f,  0.382683432365090f,  0.707106781186548f,  0.923879532511287f, \
                   1.0f,  0.923879532511287f,  0.707106781186548f,  0.382683432365090f, \
                   0.0f, -0.382683432365090f, -0.707106781186548f, -0.923879532511287f, \
                  -1.0f, -0.923879532511287f, -0.707106781186548f, -0.382683432365090f }

// 8-point inverse DFT (kernel e^{+2pi i km/8}), natural in/out order
__device__ __forceinline__ void dft8(float* xr, float* xi) {
    const float r = 0.70710678118654752f;
    float t0r = xr[0]+xr[4], t0i = xi[0]+xi[4];
    float t1r = xr[0]-xr[4], t1i = xi[0]-xi[4];
    float t2r = xr[2]+xr[6], t2i = xi[2]+xi[6];
    float t3r = xr[2]-xr[6], t3i = xi[2]-xi[6];
    float E0r = t0r+t2r, E0i = t0i+t2i;
    float E2r = t0r-t2r, E2i = t0i-t2i;
    float E1r = t1r-t3i, E1i = t1i+t3r;
    float E3r = t1r+t3i, E3i = t1i-t3r;
    float u0r = xr[1]+xr[5], u0i = xi[1]+xi[5];
    float u1r = xr[1]-xr[5], u1i = xi[1]-xi[5];
    float u2r = xr[3]+xr[7], u2i = xi[3]+xi[7];
    float u3r = xr[3]-xr[7], u3i = xi[3]-xi[7];
    float O0r = u0r+u2r, O0i = u0i+u2i;
    float O2r = u0r-u2r, O2i = u0i-u2i;
    float O1r = u1r-u3i, O1i = u1i+u3r;
    float O3r = u1r+u3i, O3i = u1i-u3r;
    float w1r =  r*(O1r - O1i), w1i = r*(O1r + O1i);   // * e^{i pi/4}
    float w2r = -O2i,           w2i = O2r;             // * i
    float w3r = -r*(O3r + O3i), w3i = r*(O3r - O3i);   // * e^{i 3pi/4}
    xr[0] = E0r + O0r;  xi[0] = E0i + O0i;
    xr[4] = E0r - O0r;  xi[4] = E0i - O0i;
    xr[1] = E1r + w1r;  xi[1] = E1i + w1i;
    xr[5] = E1r - w1r;  xi[5] = E1i - w1i;
    xr[2] = E2r + w2r;  xi[2] = E2i + w2i;
    xr[6] = E2r - w2r;  xi[6] = E2i - w2i;
    xr[3] = E3r + w3r;  xi[3] = E3i + w3i;
    xr[7] = E3r - w3r;  xi[7] = E3i - w3i;
}

// ---------------- transpose: z[ch][f][t] -> zt[ch][t][f], 64x64 float4 tiles ----------------
// Also handles the f=2048 edge row (folded-in edge2048): blocks with f0==1984 copy
// z[ch][2048][t0..t0+63] -> zt[ch][t][2048] for their t-range.
__global__ __launch_bounds__(256) void transpose64(
    const float* __restrict__ z, float* __restrict__ zt)
{
    __shared__ float tile[64][65];
    const int ch = blockIdx.z;
    const int f0 = blockIdx.x * 64;
    const int t0 = blockIdx.y * 64;
    const int tx = threadIdx.x & 15;
    const int ty = threadIdx.x >> 4;
    const float* src = z + (size_t)ch * NBINS * TFRAMES;
    float* dst = zt + (size_t)ch * TFRAMES * RS;

    #pragma unroll
    for (int k = 0; k < 4; ++k) {
        int fl = ty + 16 * k;
        float4 v = *(const float4*)(src + (size_t)(f0 + fl) * TFRAMES + t0 + 4 * tx);
        tile[fl][4 * tx + 0] = v.x;
        tile[fl][4 * tx + 1] = v.y;
        tile[fl][4 * tx + 2] = v.z;
        tile[fl][4 * tx + 3] = v.w;
    }
    __syncthreads();
    #pragma unroll
    for (int k = 0; k < 4; ++k) {
        int tl = ty + 16 * k;
        float4 v = make_float4(tile[4 * tx + 0][tl], tile[4 * tx + 1][tl],
                               tile[4 * tx + 2][tl], tile[4 * tx + 3][tl]);
        *(float4*)(dst + (size_t)(t0 + tl) * RS + f0 + 4 * tx) = v;
    }
    // edge row f=2048 (one 64-wide strip per t-tile; only the f0==1984 block column does it)
    if (f0 == 1984 && threadIdx.x < 64) {
        int t = t0 + threadIdx.x;
        dst[(size_t)t * RS + 2048] = src[(size_t)2048 * TFRAMES + t];
    }
}

// ---------------- real-IFFT path: 4 frames/block via 2048-pt complex IFFT ----------------
// Hermitian structure: Im(ifft) = (b0 + (-1)^n b2048)/N  -> computed in normalize.
// Re(ifft) = irfft(Hermitianized half): pack Y[k] = A[k] + i B[k], k<2048,
//   A[k]=H[k]+conj(H[2048-k]), B[k]=(H[k]-conj(H[2048-k]))e^{2pi i k/4096},
// then y = sum_k Y[k] e^{2pi i km/2048}; x[2m]=Re(y)/4096, x[2m+1]=Im(y)/4096.
// 2048 = 8*8*8*4, 8 pts/thread, 3 LDS shuffles (<=2-way banked), dbuf LDS, 3 barriers/frame.
// OLA tiling: frame t=4g+k4, m=T+256mp -> sample n=512mp+2T(+1); slot=mp+2k4 (0..13),
// 512-sample slots; group tile [Sc, Sc+8192), Sc=4096g-2048; parity planes as before.
// Gap zeroing folded in: block 0 zeroes plane-1 head [0,2048); block 1023 zeroes
// plane-0 tail [P0TAIL, LOUT). No other block writes those regions.
__global__ __launch_bounds__(256, 3) void fft4(
    const float* __restrict__ zt,      // [2][TFRAMES][RS]
    float* __restrict__ planes)        // [2 planes][LOUT] (real channel only)
{
    __shared__ float LRe[2][2048];
    __shared__ float LIm[2][2048];
    const int g = blockIdx.x;
    const int T = threadIdx.x;
    const float C16[16] = C16_INIT;
    const float S16[16] = S16_INIT;

    // twiddle bases depend only on T -> hoisted out of the frame loop
    float cT, sT;  __sincosf((float)T * (6.283185307179586f / 4096.0f), &sT, &cT);
    float c2, s2;  __sincosf((float)(T >> 5) * (6.283185307179586f / 64.0f), &s2, &c2);
    const int alpha = ((T >> 2) & 7) | ((T >> 5) << 3);
    float c3, s3;  __sincosf((float)alpha * (6.283185307179586f / 512.0f), &s3, &c3);
    float cD, sD;  __sincosf((float)T * (6.283185307179586f / 2048.0f), &sD, &cD);

    const float K   = 4.4703483581542969e-8f;   // 0.5*(1.5/NFFT)/NFFT
    const float cd4 = 0.99999882345170188f;     // cos(2pi/4096)
    const float sd4 = 1.5339801862847655e-3f;   // sin(2pi/4096)

    float accE[14], accO[14];
    #pragma unroll
    for (int i = 0; i < 14; ++i) { accE[i] = 0.0f; accO[i] = 0.0f; }

    int b = 0;
    #pragma unroll
    for (int k4 = 0; k4 < 4; ++k4) {
        const int t = 4 * g + k4;
        const float* rowr = zt + (size_t)t * RS;
        const float* rowi = zt + (size_t)TFRAMES * RS + (size_t)t * RS;
        float xr[8], xi[8];

        // ---- stage 1: load + Y-pack + 8-pt DFT over kA (k = T + 256*kA) ----
        #pragma unroll
        for (int kA = 0; kA < 8; ++kA) {
            int k = T + (kA << 8);
            float u  = rowr[k],        v  = rowi[k];
            float pp = rowr[2048 - k], qq = rowi[2048 - k];
            if (T == 0 && kA == 0) { v = 0.0f; qq = 0.0f; }  // bins 0/2048: drop imag
            float ck = cT * C16[kA] - sT * S16[kA];          // e^{2pi i k/4096}
            float sk = sT * C16[kA] + cT * S16[kA];
            float dr = u - pp, di = v + qq;
            xr[kA] = (u + pp) - (dr * sk + di * ck);
            xi[kA] = (v - qq) + (dr * ck - di * sk);
        }
        dft8(xr, xi);
        #pragma unroll
        for (int m1 = 0; m1 < 8; ++m1) {
            int a = (m1 << 8) | T;
            LRe[b][a] = xr[m1];  LIm[b][a] = xi[m1];
        }
        __syncthreads();

        // ---- stage 2: 8-pt DFT over kB, pre-twiddle e^{2pi i kB m1/64}, m1=T>>5 ----
        {
            float cw = 1.0f, sw = 0.0f;
            #pragma unroll
            for (int kB = 0; kB < 8; ++kB) {
                int a = ((T >> 5) << 8) | (kB << 5) | (T & 31);
                float vr = LRe[b][a], vi = LIm[b][a];
                xr[kB] = vr * cw - vi * sw;
                xi[kB] = vr * sw + vi * cw;
                float ncw = cw * c2 - sw * s2;
                sw = cw * s2 + sw * c2;  cw = ncw;
            }
        }
        dft8(xr, xi);
        b ^= 1;
        #pragma unroll
        for (int m2 = 0; m2 < 8; ++m2) {
            int a = (m2 << 8) | T;
            a ^= ((a >> 5) & 7) << 2;          // swizzle: both sides <=2-way
            LRe[b][a] = xr[m2];  LIm[b][a] = xi[m2];
        }
        __syncthreads();

        // ---- stage 3: 8-pt DFT over kC, pre-twiddle e^{2pi i kC alpha/512} ----
        {
            float cw = 1.0f, sw = 0.0f;
            #pragma unroll
            for (int kC = 0; kC < 8; ++kC) {
                int a = ((T >> 5) << 8) | (((T >> 2) & 7) << 5) | (kC << 2) | (T & 3);
                a ^= ((a >> 5) & 7) << 2;
                float vr = LRe[b][a], vi = LIm[b][a];
                xr[kC] = vr * cw - vi * sw;
                xi[kC] = vr * sw + vi * cw;
                float ncw = cw * c3 - sw * s3;
                sw = cw * s3 + sw * c3;  cw = ncw;
            }
        }
        dft8(xr, xi);
        b ^= 1;
        #pragma unroll
        for (int m3 = 0; m3 < 8; ++m3) {
            int a = (m3 << 8) | T;
            a ^= (a >> 5) & 3;                 // swizzle: both sides <=2-way
            LRe[b][a] = xr[m3];  LIm[b][a] = xi[m3];
        }
        __syncthreads();

        // ---- stage 4: two 4-pt DFTs over kD + window + register OLA ----
        #pragma unroll
        for (int hi = 0; hi < 2; ++hi) {
            // base twiddle wb = e^{2pi i (T + 256*hi)/2048}
            float cb = hi ? (cD * C16[2] - sD * S16[2]) : cD;
            float sb = hi ? (sD * C16[2] + cD * S16[2]) : sD;
            float zr[4], zi[4];
            float cw = 1.0f, sw = 0.0f;
            #pragma unroll
            for (int kD = 0; kD < 4; ++kD) {
                int a = (((T >> 6) + 4 * hi) << 8) | (((T >> 3) & 7) << 5) | ((T & 7) << 2) | kD;
                a ^= (a >> 5) & 3;
                float vr = LRe[b][a], vi = LIm[b][a];
                zr[kD] = vr * cw - vi * sw;
                zi[kD] = vr * sw + vi * cw;
                float ncw = cw * cb - sw * sb;
                sw = cw * sb + sw * cb;  cw = ncw;
            }
            float e0r = zr[0] + zr[2], e0i = zi[0] + zi[2];
            float e1r = zr[0] - zr[2], e1i = zi[0] - zi[2];
            float o0r = zr[1] + zr[3], o0i = zi[1] + zi[3];
            float o1r = zr[1] - zr[3], o1i = zi[1] - zi[3];
            float yr[4], yi[4];
            yr[0] = e0r + o0r;  yi[0] = e0i + o0i;
            yr[2] = e0r - o0r;  yi[2] = e0i - o0i;
            yr[1] = e1r - o1i;  yi[1] = e1i + o1r;
            yr[3] = e1r + o1i;  yi[3] = e1i - o1r;
            #pragma unroll
            for (int m4 = 0; m4 < 4; ++m4) {
                int mp = hi + 2 * m4;          // m = T + 256*mp
                float cm = cD * C16[2 * mp] - sD * S16[2 * mp];   // cos(2pi m/2048)
                float sm = sD * C16[2 * mp] + cD * S16[2 * mp];
                float we = (1.0f - cm) * K;                        // window(2m)*scale
                float co = cm * cd4 - sm * sd4;
                float wo = (1.0f - co) * K;                        // window(2m+1)*scale
                int slot = mp + 2 * k4;
                accE[slot] += yr[m4] * we;
                accO[slot] += yi[m4] * wo;
            }
        }
        b ^= 1;
    }

    // ---- plain coalesced float2 stores; slots 14,15 zero-pad tile the plane ----
    const int plane = g & 1;
    float* pr = planes + (size_t)plane * LOUT;
    const int Sc = (g << 12) - 2048;
    #pragma unroll
    for (int s = 0; s < 16; ++s) {
        int Q = Sc + (s << 9) + 2 * T;
        if ((unsigned)Q < (unsigned)LOUT) {
            float2 v;
            v.x = (s < 14) ? accE[s] : 0.0f;
            v.y = (s < 14) ? accO[s] : 0.0f;
            *(float2*)(pr + Q) = v;
        }
    }
    // ---- folded gap zeroing (regions no tile covers) ----
    if (g == 0) {
        float* p1 = planes + (size_t)LOUT;          // plane-1 head [0,2048)
        #pragma unroll
        for (int i = 0; i < 8; ++i) p1[T + 256 * i] = 0.0f;
    }
    if (g == 1023) {
        float* p0 = planes;                          // plane-0 tail [P0TAIL, LOUT): 1024 floats
        #pragma unroll
        for (int i = 0; i < 4; ++i) p0[P0TAIL + T + 256 * i] = 0.0f;
    }
}

// ---------------- sum 2 planes (real) + analytic imag channel + normalize ----------------
__global__ __launch_bounds__(256) void normalize_planes(
    const float* __restrict__ planes,    // [2][LOUT]
    const float* __restrict__ z,         // original input: b rows for imag channel
    const float* __restrict__ window,
    float* __restrict__ out)
{
    int idx = blockIdx.x * 256 + threadIdx.x;
    int p = idx * 4;
    if (p >= LOUT) return;
    const float* b0  = z + (size_t)NBINS * TFRAMES;                            // z[1][0][t]
    const float* b2k = z + (size_t)NBINS * TFRAMES + (size_t)2048 * TFRAMES;   // z[1][2048][t]
    float4 a0 = *(const float4*)(planes + p);
    float4 a1 = *(const float4*)(planes + (size_t)LOUT + p);
    float re[4] = {a0.x + a1.x, a0.y + a1.y, a0.z + a1.z, a0.w + a1.w};
    const float INV_N = 1.0f / 4096.0f;
    if (p >= 1024 && p < LOUT - 1024) {
        const float inv = (float)NFFT / 3.0f;          // interior wsum = 3/4096 exactly
        float im[4];
        #pragma unroll
        for (int e = 0; e < 4; ++e) {
            int P = p + e + CROP;
            int th = P >> 10;                          // t_hi; frames th-3..th overlap
            int n0 = P & 1023;
            float sn, cn;
            __sincosf((float)n0 * (6.283185307179586f / 4096.0f), &sn, &cn);
            const float WK = 1.8310546875e-4f;         // 0.5*1.5/4096
            // w[n0+1024j]: cos terms {cn, -sn, -cn, sn}
            float w0 = (1.0f - cn) * WK;
            float w1 = (1.0f + sn) * WK;
            float w2 = (1.0f + cn) * WK;
            float w3 = (1.0f - sn) * WK;
            float s1 = w0 * b0[th]  + w1 * b0[th - 1]  + w2 * b0[th - 2]  + w3 * b0[th - 3];
            float s2 = w0 * b2k[th] + w1 * b2k[th - 1] + w2 * b2k[th - 2] + w3 * b2k[th - 3];
            float sgn = (P & 1) ? -1.0f : 1.0f;
            im[e] = (s1 + sgn * s2) * (1.0f / 3.0f);   // (1/4096)*(4096/3)
            re[e] *= inv;
        }
        *(float4*)(out + p) = make_float4(re[0], re[1], re[2], re[3]);
        *(float4*)(out + (size_t)LOUT + p) = make_float4(im[0], im[1], im[2], im[3]);
    } else {
        for (int e = 0; e < 4; ++e) {
            int P = p + e + CROP;
            int t_hi = min(TFRAMES - 1, P >> 10);
            int t_lo = max(0, (P - (NFFT - HOP)) >> 10);
            float ws = 0.0f, s1 = 0.0f, s2 = 0.0f;
            for (int tt = t_lo; tt <= t_hi; ++tt) {
                float w = window[P - (tt << 10)];
                ws += w;
                s1 += w * b0[tt];
                s2 += w * b2k[tt];
            }
            float inv = (ws >= 1e-6f) ? (1.0f / ws) : 1.0f;
            float sgn = (P & 1) ? -1.0f : 1.0f;
            out[p + e]                 = re[e] * inv;
            out[(size_t)LOUT + p + e]  = (s1 + sgn * s2) * INV_N * inv;
        }
    }
}

// ================= fallback path (ws too small for planes): atomic version =================
__global__ __launch_bounds__(256) void edge2048(
    const float* __restrict__ z, float* __restrict__ zt)
{
    int i = blockIdx.x * 256 + threadIdx.x;      // 0 .. 8191
    int ch = i >> 12, t = i & 4095;
    zt[(size_t)ch * TFRAMES * RS + (size_t)t * RS + 2048] =
        z[(size_t)ch * NBINS * TFRAMES + (size_t)2048 * TFRAMES + t];
}

__global__ __launch_bounds__(256) void fft_reg(
    const float* __restrict__ zt, float* __restrict__ out)
{
    __shared__ float LRe[NFFT];
    __shared__ float LIm[NFFT];
    const int t = blockIdx.x;
    const int T = threadIdx.x;
    const float C16[16] = C16_INIT;
    const float S16[16] = S16_INIT;
    const float* rowr = zt + (size_t)t * RS;
    const float* rowi = zt + (size_t)TFRAMES * RS + (size_t)t * RS;
    float xr[16], xi[16];
    #pragma unroll
    for (int m = 0; m < 16; ++m) {
        int r = ((m & 3) << 2) | (m >> 2);
        int n = (m << 8) + T;
        if (n <= 2048) { xr[r] = rowr[n]; xi[r] = rowi[n]; }
        else { int f = NFFT - n; xr[r] = rowr[f]; xi[r] = -rowi[f]; }
    }
    #pragma unroll
    for (int a = 0; a < 4; ++a)
        b4(xr[4*a], xi[4*a], xr[4*a+1], xi[4*a+1], xr[4*a+2], xi[4*a+2], xr[4*a+3], xi[4*a+3]);
    b4(xr[0], xi[0], xr[4], xi[4], xr[8], xi[8], xr[12], xi[12]);
    #pragma unroll
    for (int r0 = 1; r0 < 4; ++r0)
        b4t(xr[r0], xi[r0], xr[r0+4], xi[r0+4], xr[r0+8], xi[r0+8], xr[r0+12], xi[r0+12],
            C16[r0], S16[r0]);
    {
        int G = ((T & 3) << 6) | (((T >> 2) & 3) << 4) | (((T >> 4) & 3) << 2) | ((T >> 6) & 3);
        int p0 = G << 4;
        #pragma unroll
        for (int r = 0; r < 16; ++r) { int a = SW1(p0 + r); LRe[a] = xr[r]; LIm[a] = xi[r]; }
    }
    __syncthreads();
    const int H = T >> 4, j = T & 15;
    #pragma unroll
    for (int s = 0; s < 16; ++s) { int a = SW1((H << 8) + (s << 4) + j); xr[s] = LRe[a]; xi[s] = LIm[a]; }
    float cb, sb;
    __sincosf((float)j * (6.283185307179586f / 256.0f), &sb, &cb);
    float cd = cb * cb - sb * sb, sd = 2.0f * cb * sb;
    float c2s = cd * cd - sd * sd, s2s = 2.0f * cd * sd;
    if (j == 0) {
        #pragma unroll
        for (int a = 0; a < 4; ++a)
            b4(xr[4*a], xi[4*a], xr[4*a+1], xi[4*a+1], xr[4*a+2], xi[4*a+2], xr[4*a+3], xi[4*a+3]);
    } else {
        #pragma unroll
        for (int a = 0; a < 4; ++a)
            b4t(xr[4*a], xi[4*a], xr[4*a+1], xi[4*a+1], xr[4*a+2], xi[4*a+2], xr[4*a+3], xi[4*a+3],
                c2s, s2s);
    }
    #pragma unroll
    for (int s0 = 0; s0 < 4; ++s0) {
        float c = cb * C16[s0] - sb * S16[s0];
        float s = sb * C16[s0] + cb * S16[s0];
        if (s0 == 0 && j == 0) b4(xr[0], xi[0], xr[4], xi[4], xr[8], xi[8], xr[12], xi[12]);
        else b4t(xr[s0], xi[s0], xr[s0+4], xi[s0+4], xr[s0+8], xi[s0+8], xr[s0+12], xi[s0+12], c, s);
    }
    __syncthreads();
    #pragma unroll
    for (int s = 0; s < 16; ++s) { int a = SW2((H << 8) + (s << 4) + j); LRe[a] = xr[s]; LIm[a] = xi[s]; }
    __syncthreads();
    #pragma unroll
    for (int m = 0; m < 16; ++m) { int a = SW2((m << 8) + T); xr[m] = LRe[a]; xi[m] = LIm[a]; }
    float c5, s5;
    __sincosf((float)T * (6.283185307179586f / 4096.0f), &s5, &c5);
    float cq = c5 * c5 - s5 * s5, sq = 2.0f * c5 * s5;
    float c4s = cq * cq - sq * sq, s4s = 2.0f * cq * sq;
    if (T == 0) {
        #pragma unroll
        for (int a = 0; a < 4; ++a)
            b4(xr[4*a], xi[4*a], xr[4*a+1], xi[4*a+1], xr[4*a+2], xi[4*a+2], xr[4*a+3], xi[4*a+3]);
    } else {
        #pragma unroll
        for (int a = 0; a < 4; ++a)
            b4t(xr[4*a], xi[4*a], xr[4*a+1], xi[4*a+1], xr[4*a+2], xi[4*a+2], xr[4*a+3], xi[4*a+3],
                c4s, s4s);
    }
    #pragma unroll
    for (int m0 = 0; m0 < 4; ++m0) {
        float c = c5 * C16[m0] - s5 * S16[m0];
        float s = s5 * C16[m0] + c5 * S16[m0];
        if (m0 == 0 && T == 0) b4(xr[0], xi[0], xr[4], xi[4], xr[8], xi[8], xr[12], xi[12]);
        else b4t(xr[m0], xi[m0], xr[m0+4], xi[m0+4], xr[m0+8], xi[m0+8], xr[m0+12], xi[m0+12], c, s);
    }
    const float K = 4.4703483581542969e-8f;
    const int base = (t << 10) - CROP;
    #pragma unroll
    for (int m = 0; m < 16; ++m) {
        float cn = c5 * C16[m] - s5 * S16[m];
        float wn = (1.0f - cn) * K;
        int P = base + (m << 8) + T;
        if (P >= 0 && P < LOUT) {
            atomicAdd(&out[P],        xr[m] * wn);
            atomicAdd(&out[LOUT + P], xi[m] * wn);
        }
    }
}

__global__ __launch_bounds__(256) void normalize_inplace(
    const float* __restrict__ window, float* __restrict__ out)
{
    int idx = blockIdx.x * 256 + threadIdx.x;
    int p = idx * 4;
    if (p >= LOUT) return;
    if (p >= 1024 && p < LOUT - 1024) {
        const float inv = (float)NFFT / 3.0f;
        float4* o0 = (float4*)(out + p);
        float4* o1 = (float4*)(out + LOUT + p);
        float4 a = *o0, b = *o1;
        a.x *= inv; a.y *= inv; a.z *= inv; a.w *= inv;
        b.x *= inv; b.y *= inv; b.z *= inv; b.w *= inv;
        *o0 = a; *o1 = b;
    } else {
        for (int e = 0; e < 4; ++e) {
            int pe = p + e;
            int P = pe + CROP;
            int t_hi = min(TFRAMES - 1, P >> 10);
            int t_lo = max(0, (P - (NFFT - HOP)) >> 10);
            float ws = 0.0f;
            for (int tt = t_lo; tt <= t_hi; ++tt) ws += window[P - (tt << 10)];
            float inv = (ws >= 1e-6f) ? (1.0f / ws) : 1.0f;
            out[pe]        *= inv;
            out[LOUT + pe] *= inv;
        }
    }
}

extern "C" void kernel_launch(void* const* d_in, const int* in_sizes, int n_in,
                              void* d_out, int out_size, void* d_ws, size_t ws_size,
                              hipStream_t stream) {
    const float* z      = (const float*)d_in[0];
    const float* window = (const float*)d_in[1];
    float* out = (float*)d_out;

    const size_t zt_floats = (size_t)2 * TFRAMES * RS;            // 16,908,288
    const size_t ws_need_B = zt_floats * sizeof(float);           // 67.6 MB (atomic path)
    const size_t ws_need_A = (zt_floats + (size_t)2 * LOUT) * sizeof(float);  // 101.2 MB

    if (ws_size >= ws_need_A) {
        float* zt     = (float*)d_ws;
        float* planes = zt + zt_floats;
        transpose64<<<dim3(32, 64, 2), 256, 0, stream>>>(z, zt);   // includes edge row
        fft4<<<TFRAMES / 4, 256, 0, stream>>>(zt, planes);         // includes gap zeroing
        normalize_planes<<<(LOUT / 4 + 255) / 256, 256, 0, stream>>>(planes, z, window, out);
    } else if (ws_size >= ws_need_B) {
        float* zt = (float*)d_ws;
        hipMemsetAsync(out, 0, (size_t)2 * LOUT * sizeof(float), stream);
        transpose64<<<dim3(32, 64, 2), 256, 0, stream>>>(z, zt);
        edge2048<<<32, 256, 0, stream>>>(z, zt);
        fft_reg<<<TFRAMES, 256, 0, stream>>>(zt, out);
        normalize_inplace<<<(LOUT / 4 + 255) / 256, 256, 0, stream>>>(window, out);
    }
}